// Round 2
// baseline (1116.189 us; speedup 1.0000x reference)
//
#include <hip/hip_runtime.h>

#define BB 4
#define NF 200000
#define NCOARSE 50000
#define CH 32
#define NPOOL 200000
#define NEDGE 800000
#define EPSV 1e-5f

// ---------------- zero ----------------
__global__ void zero_kernel(int* __restrict__ p, int n) {
    int i = blockIdx.x * blockDim.x + threadIdx.x;
    int stride = gridDim.x * blockDim.x;
    for (; i < n; i += stride) p[i] = 0;
}

// ---------------- histogram ----------------
__global__ void hist_kernel(const int* __restrict__ dst, int n, int* __restrict__ cnt) {
    int i = blockIdx.x * blockDim.x + threadIdx.x;
    int stride = gridDim.x * blockDim.x;
    for (; i < n; i += stride) atomicAdd(&cnt[dst[i]], 1);
}

// ---------------- single-block exclusive scan over n counters ----------------
// cnt_next holds counts on entry; on exit rowp[i]=exclusive prefix, rowp[n]=total,
// and cnt_next[i]=exclusive prefix (running cursor for scatter).
__global__ __launch_bounds__(1024)
void scan_kernel(int* __restrict__ cnt_next, int* __restrict__ rowp, int n) {
    __shared__ int lds[1024];
    int t = threadIdx.x;
    int chunk = (n + 1023) / 1024;
    int s = t * chunk;
    int e = min(s + chunk, n);
    int sum = 0;
    for (int i = s; i < e; ++i) sum += cnt_next[i];
    lds[t] = sum;
    __syncthreads();
    for (int off = 1; off < 1024; off <<= 1) {
        int v = (t >= off) ? lds[t - off] : 0;
        __syncthreads();
        lds[t] += v;
        __syncthreads();
    }
    int base = lds[t] - sum;   // exclusive prefix of this chunk
    for (int i = s; i < e; ++i) {
        int cv = cnt_next[i];
        rowp[i] = base;
        cnt_next[i] = base;
        base += cv;
    }
    if (t == 1023) rowp[n] = lds[1023];
}

// ---------------- scatter into CSR ----------------
__global__ void scatter_kernel(const int* __restrict__ src, const int* __restrict__ dst,
                               const float* __restrict__ attr, int n,
                               int* __restrict__ next, int* __restrict__ s_srcs,
                               float* __restrict__ s_wts) {
    int i = blockIdx.x * blockDim.x + threadIdx.x;
    int stride = gridDim.x * blockDim.x;
    for (; i < n; i += stride) {
        int d = dst[i];
        int pos = atomicAdd(&next[d], 1);
        s_srcs[pos] = src[i];
        s_wts[pos] = attr[i];
    }
}

// ---------------- pool gather: pooled[b][n][c] = sum_e attr*x[b][src][c] ----------------
__global__ __launch_bounds__(256)
void pool_kernel(const float* __restrict__ x, float* __restrict__ pooled,
                 const int* __restrict__ rowp, const int* __restrict__ srcs,
                 const float* __restrict__ wts) {
    const int tid = threadIdx.x;
    const int c = tid & 31;
    const int g = tid >> 5;               // 8 node-groups per block
    const int ntiles = (NCOARSE / 8) * BB;
    for (int tile = blockIdx.x; tile < ntiles; tile += gridDim.x) {
        const int b = tile / (NCOARSE / 8);
        const int nt = tile % (NCOARSE / 8);
        const int n = nt * 8 + g;
        const float* xb = x + (size_t)b * NF * CH;
        int e0 = rowp[n], e1 = rowp[n + 1];
        float a0 = 0.f, a1 = 0.f, a2 = 0.f, a3 = 0.f;
        int e = e0;
        for (; e + 4 <= e1; e += 4) {
            int s0 = srcs[e], s1 = srcs[e + 1], s2 = srcs[e + 2], s3 = srcs[e + 3];
            float w0 = wts[e], w1 = wts[e + 1], w2 = wts[e + 2], w3 = wts[e + 3];
            a0 += w0 * xb[s0 * CH + c];
            a1 += w1 * xb[s1 * CH + c];
            a2 += w2 * xb[s2 * CH + c];
            a3 += w3 * xb[s3 * CH + c];
        }
        for (; e < e1; ++e) a0 += wts[e] * xb[srcs[e] * CH + c];
        pooled[(size_t)b * NCOARSE * CH + n * CH + c] = (a0 + a1) + (a2 + a3);
    }
}

// ---------------- weighted GraphConv ----------------
// out[b][n][c] = bias[c] + sum_k h[b][n][k]*Wr[k][c] + sum_k agg[b][n][k]*Wn[k][c]
// agg[b][n][k] = sum_{e: dst=n} w[e]*h[b][src[e]][k]
__global__ __launch_bounds__(256)
void gconv_kernel(const float* __restrict__ hin, float* __restrict__ hout,
                  const int* __restrict__ rowp, const int* __restrict__ srcs,
                  const float* __restrict__ wts,
                  const float* __restrict__ Wr, const float* __restrict__ Wn,
                  const float* __restrict__ bias) {
    const int tid = threadIdx.x;
    const int c = tid & 31;
    const int g = tid >> 5;
    float wr[32], wn[32];
#pragma unroll
    for (int k = 0; k < 32; ++k) {
        wr[k] = Wr[k * 32 + c];
        wn[k] = Wn[k * 32 + c];
    }
    const float bc = bias[c];
    const int ntiles = (NCOARSE / 8) * BB;
    for (int tile = blockIdx.x; tile < ntiles; tile += gridDim.x) {
        const int b = tile / (NCOARSE / 8);
        const int nt = tile % (NCOARSE / 8);
        const int n = nt * 8 + g;
        const float* hb = hin + (size_t)b * NCOARSE * CH;
        float xv = hb[n * CH + c];
        int e0 = rowp[n], e1 = rowp[n + 1];
        float a0 = 0.f, a1 = 0.f, a2 = 0.f, a3 = 0.f;
        int e = e0;
        for (; e + 4 <= e1; e += 4) {
            int s0 = srcs[e], s1 = srcs[e + 1], s2 = srcs[e + 2], s3 = srcs[e + 3];
            float w0 = wts[e], w1 = wts[e + 1], w2 = wts[e + 2], w3 = wts[e + 3];
            a0 += w0 * hb[s0 * CH + c];
            a1 += w1 * hb[s1 * CH + c];
            a2 += w2 * hb[s2 * CH + c];
            a3 += w3 * hb[s3 * CH + c];
        }
        for (; e < e1; ++e) a0 += wts[e] * hb[srcs[e] * CH + c];
        float agg = (a0 + a1) + (a2 + a3);
        float acc = bc;
#pragma unroll
        for (int k = 0; k < 32; ++k) {
            acc += __shfl(xv, k, 32) * wr[k];
            acc += __shfl(agg, k, 32) * wn[k];
        }
        hout[(size_t)b * NCOARSE * CH + n * CH + c] = acc;
    }
}

// ---------------- instance-norm stats (partial sums via atomics) ----------------
__global__ __launch_bounds__(256)
void stats_kernel(const float* __restrict__ h, float* __restrict__ sums,
                  float* __restrict__ sumsq) {
    __shared__ float l1[256], l2[256];
    const int b = blockIdx.y;
    const int c = threadIdx.x & 31;
    const float* hb = h + (size_t)b * NCOARSE * CH;
    float s = 0.f, sq = 0.f;
    int stride = gridDim.x * blockDim.x;              // multiple of 32
    for (int i = blockIdx.x * blockDim.x + threadIdx.x; i < NCOARSE * CH; i += stride) {
        float v = hb[i];
        s += v;
        sq += v * v;
    }
    l1[threadIdx.x] = s;
    l2[threadIdx.x] = sq;
    __syncthreads();
    if (threadIdx.x < 32) {
        float ts = 0.f, tq = 0.f;
#pragma unroll
        for (int g = 0; g < 8; ++g) {
            ts += l1[g * 32 + c];
            tq += l2[g * 32 + c];
        }
        atomicAdd(&sums[b * 32 + c], ts);
        atomicAdd(&sumsq[b * 32 + c], tq);
    }
}

__global__ void stats_fin(const float* __restrict__ sums, const float* __restrict__ sumsq,
                          float* __restrict__ mean, float* __restrict__ rstd) {
    int i = threadIdx.x;
    if (i < 128) {
        float m = sums[i] / (float)NCOARSE;
        float v = sumsq[i] / (float)NCOARSE - m * m;
        mean[i] = m;
        rstd[i] = rsqrtf(v + EPSV);
    }
}

__global__ void norm_kernel(const float* __restrict__ in, float* __restrict__ out,
                            const float* __restrict__ mean, const float* __restrict__ rstd) {
    const int total = BB * NCOARSE * CH;
    int stride = gridDim.x * blockDim.x;
    for (int i = blockIdx.x * blockDim.x + threadIdx.x; i < total; i += stride) {
        int c = i & 31;
        int b = i / (NCOARSE * CH);
        out[i] = (in[i] - mean[b * 32 + c]) * rstd[b * 32 + c];
    }
}

extern "C" void kernel_launch(void* const* d_in, const int* in_sizes, int n_in,
                              void* d_out, int out_size, void* d_ws, size_t ws_size,
                              hipStream_t stream) {
    const float* x         = (const float*)d_in[0];
    const int*   pool_src  = (const int*)d_in[1];
    const int*   pool_dst  = (const int*)d_in[2];
    const float* pool_attr = (const float*)d_in[3];
    const int*   edge_src  = (const int*)d_in[4];
    const int*   edge_dst  = (const int*)d_in[5];
    const float* edge_attr = (const float*)d_in[6];
    // d_in[7] = num_coarse (compile-time constant NCOARSE)
    const float* Wr1 = (const float*)d_in[8];
    const float* Wn1 = (const float*)d_in[9];
    const float* b1  = (const float*)d_in[10];
    const float* Wr2 = (const float*)d_in[11];
    const float* Wn2 = (const float*)d_in[12];
    const float* b2  = (const float*)d_in[13];
    const float* Wr3 = (const float*)d_in[14];
    const float* Wn3 = (const float*)d_in[15];
    const float* b3  = (const float*)d_in[16];
    const float* Wr4 = (const float*)d_in[17];
    const float* Wn4 = (const float*)d_in[18];
    const float* b4  = (const float*)d_in[19];

    // ---- workspace layout (~34.5 MB; d_out doubles as ping-pong buffer) ----
    char* w = (char*)d_ws;
    float* bufA = (float*)w;            w += (size_t)BB * NCOARSE * CH * 4;   // 25.6 MB
    int*   poolRow  = (int*)w;          w += (size_t)(NCOARSE + 1) * 4;
    int*   poolNext = (int*)w;          w += (size_t)NCOARSE * 4;
    int*   poolS    = (int*)w;          w += (size_t)NPOOL * 4;
    float* poolW    = (float*)w;        w += (size_t)NPOOL * 4;
    int*   edgeRow  = (int*)w;          w += (size_t)(NCOARSE + 1) * 4;
    int*   edgeNext = (int*)w;          w += (size_t)NCOARSE * 4;
    int*   edgeS    = (int*)w;          w += (size_t)NEDGE * 4;
    float* edgeW    = (float*)w;        w += (size_t)NEDGE * 4;
    float* stats    = (float*)w;        w += 512 * 4;   // sum[128] sumsq[128] mean[128] rstd[128]

    float* out = (float*)d_out;

    // ---- CSR build (once per call; reused by all 4 convs) ----
    zero_kernel<<<196, 256, 0, stream>>>(poolNext, NCOARSE);
    zero_kernel<<<196, 256, 0, stream>>>(edgeNext, NCOARSE);
    zero_kernel<<<1, 256, 0, stream>>>((int*)stats, 256);
    hist_kernel<<<782, 256, 0, stream>>>(pool_dst, NPOOL, poolNext);
    hist_kernel<<<3125, 256, 0, stream>>>(edge_dst, NEDGE, edgeNext);
    scan_kernel<<<1, 1024, 0, stream>>>(poolNext, poolRow, NCOARSE);
    scan_kernel<<<1, 1024, 0, stream>>>(edgeNext, edgeRow, NCOARSE);
    scatter_kernel<<<782, 256, 0, stream>>>(pool_src, pool_dst, pool_attr, NPOOL,
                                            poolNext, poolS, poolW);
    scatter_kernel<<<3125, 256, 0, stream>>>(edge_src, edge_dst, edge_attr, NEDGE,
                                             edgeNext, edgeS, edgeW);

    // ---- pipeline: pool->A, g1: A->out, g2: out->A, norm: A->out, g3: out->A, g4: A->out
    pool_kernel<<<2048, 256, 0, stream>>>(x, bufA, poolRow, poolS, poolW);
    gconv_kernel<<<2048, 256, 0, stream>>>(bufA, out, edgeRow, edgeS, edgeW, Wr1, Wn1, b1);
    gconv_kernel<<<2048, 256, 0, stream>>>(out, bufA, edgeRow, edgeS, edgeW, Wr2, Wn2, b2);
    stats_kernel<<<dim3(256, 4), 256, 0, stream>>>(bufA, stats, stats + 128);
    stats_fin<<<1, 128, 0, stream>>>(stats, stats + 128, stats + 256, stats + 384);
    norm_kernel<<<2048, 256, 0, stream>>>(bufA, out, stats + 256, stats + 384);
    gconv_kernel<<<2048, 256, 0, stream>>>(out, bufA, edgeRow, edgeS, edgeW, Wr3, Wn3, b3);
    gconv_kernel<<<2048, 256, 0, stream>>>(bufA, out, edgeRow, edgeS, edgeW, Wr4, Wn4, b4);
}

// Round 3
// 1006.576 us; speedup vs baseline: 1.1089x; 1.1089x over previous
//
#include <hip/hip_runtime.h>

#define BB 4
#define NFINE 200000
#define NC 50000
#define CH 32
#define NPOOL 200000
#define NEDGE 800000
#define EPSV 1e-5f
#define NWAVES 8192   // 2048 blocks * 4 waves/block

// ---------------- broadcast lane K within each 32-lane group ----------------
template<int K>
__device__ __forceinline__ float2 bcast2(float2 v) {
    union { float f; int i; } x, y;
    x.f = v.x; y.f = v.y;
    x.i = __builtin_amdgcn_ds_swizzle(x.i, (K << 5));   // BitMode: and=0, or=K
    y.i = __builtin_amdgcn_ds_swizzle(y.i, (K << 5));
    return make_float2(x.f, y.f);
}

template<int K>
struct MM {
    static __device__ __forceinline__ void run(const float2& xv, const float2& ag,
                                               const float* wr, const float* wn, float2& acc) {
        MM<K - 1>::run(xv, ag, wr, wn, acc);
        float2 xb = bcast2<K>(xv);
        float2 ab = bcast2<K>(ag);
        acc.x += xb.x * wr[K] + ab.x * wn[K];
        acc.y += xb.y * wr[K] + ab.y * wn[K];
    }
};
template<>
struct MM<-1> {
    static __device__ __forceinline__ void run(const float2&, const float2&,
                                               const float*, const float*, float2&) {}
};

// ---------------- zero ----------------
__global__ void zero_kernel(int* __restrict__ p, int n) {
    int i = blockIdx.x * blockDim.x + threadIdx.x;
    int stride = gridDim.x * blockDim.x;
    for (; i < n; i += stride) p[i] = 0;
}

// ---------------- histogram ----------------
__global__ void hist_kernel(const int* __restrict__ dst, int n, int* __restrict__ cnt) {
    int i = blockIdx.x * blockDim.x + threadIdx.x;
    int stride = gridDim.x * blockDim.x;
    for (; i < n; i += stride) atomicAdd(&cnt[dst[i]], 1);
}

// ---------------- single-block exclusive scan ----------------
__global__ __launch_bounds__(1024)
void scan_kernel(int* __restrict__ cnt_next, int* __restrict__ rowp, int n) {
    __shared__ int lds[1024];
    int t = threadIdx.x;
    int chunk = (n + 1023) / 1024;
    int s = t * chunk;
    int e = min(s + chunk, n);
    int sum = 0;
    for (int i = s; i < e; ++i) sum += cnt_next[i];
    lds[t] = sum;
    __syncthreads();
    for (int off = 1; off < 1024; off <<= 1) {
        int v = (t >= off) ? lds[t - off] : 0;
        __syncthreads();
        lds[t] += v;
        __syncthreads();
    }
    int base = lds[t] - sum;
    for (int i = s; i < e; ++i) {
        int cv = cnt_next[i];
        rowp[i] = base;
        cnt_next[i] = base;
        base += cv;
    }
    if (t == 1023) rowp[n] = lds[1023];
}

// ---------------- scatter into CSR ----------------
__global__ void scatter_kernel(const int* __restrict__ src, const int* __restrict__ dst,
                               const float* __restrict__ attr, int n,
                               int* __restrict__ next, int* __restrict__ s_srcs,
                               float* __restrict__ s_wts) {
    int i = blockIdx.x * blockDim.x + threadIdx.x;
    int stride = gridDim.x * blockDim.x;
    for (; i < n; i += stride) {
        int d = dst[i];
        int pos = atomicAdd(&next[d], 1);
        s_srcs[pos] = src[i];
        s_wts[pos] = attr[i];
    }
}

// ---------------- pool: x[B][NF][CH] -> pooled[N][CH][B] ----------------
// wave per coarse node; lane = (c = lane&31, bh = lane>>5), batches {2bh, 2bh+1}
__global__ __launch_bounds__(256)
void pool_kernel(const float* __restrict__ x, float* __restrict__ pooled,
                 const int* __restrict__ rowp, const int* __restrict__ srcs,
                 const float* __restrict__ wts) {
    const int tid = threadIdx.x;
    const int lane = tid & 63;
    const int c = lane & 31;
    const int bh = lane >> 5;
    const int wid = blockIdx.x * 4 + (tid >> 6);
    const float* __restrict__ xA = x + (size_t)(2 * bh) * NFINE * CH;
    const float* __restrict__ xB = x + (size_t)(2 * bh + 1) * NFINE * CH;
    for (int n = wid; n < NC; n += NWAVES) {
        int e0 = rowp[n], e1 = rowp[n + 1];
        float2 a0 = {0, 0}, a1 = {0, 0}, a2 = {0, 0}, a3 = {0, 0};
        int e = e0;
        for (; e + 4 <= e1; e += 4) {
            int s0 = srcs[e], s1 = srcs[e + 1], s2 = srcs[e + 2], s3 = srcs[e + 3];
            float w0 = wts[e], w1 = wts[e + 1], w2 = wts[e + 2], w3 = wts[e + 3];
            a0.x += w0 * xA[s0 * CH + c]; a0.y += w0 * xB[s0 * CH + c];
            a1.x += w1 * xA[s1 * CH + c]; a1.y += w1 * xB[s1 * CH + c];
            a2.x += w2 * xA[s2 * CH + c]; a2.y += w2 * xB[s2 * CH + c];
            a3.x += w3 * xA[s3 * CH + c]; a3.y += w3 * xB[s3 * CH + c];
        }
        for (; e < e1; ++e) {
            float w0 = wts[e];
            int s0 = srcs[e];
            a0.x += w0 * xA[s0 * CH + c];
            a0.y += w0 * xB[s0 * CH + c];
        }
        ((float2*)pooled)[(n * CH + c) * 2 + bh] =
            make_float2((a0.x + a1.x) + (a2.x + a3.x), (a0.y + a1.y) + (a2.y + a3.y));
    }
}

// ---------------- weighted GraphConv on [N][CH][B] layout ----------------
// wave per node, all 4 batches (float2/lane). Optionally normalize input on
// the fly (fused InstanceNorm) and/or emit final [B][N][CH] layout.
template<bool NORM, bool OUTBNC>
__global__ __launch_bounds__(256)
void gconv_kernel(const float* __restrict__ hin, float* __restrict__ hout,
                  const int* __restrict__ rowp, const int* __restrict__ srcs,
                  const float* __restrict__ wts,
                  const float* __restrict__ Wr, const float* __restrict__ Wn,
                  const float* __restrict__ bias,
                  const float* __restrict__ meanp, const float* __restrict__ rstdp) {
    const int tid = threadIdx.x;
    const int lane = tid & 63;
    const int c = lane & 31;
    const int bh = lane >> 5;
    const int wid = blockIdx.x * 4 + (tid >> 6);

    float wr[CH], wn[CH];
#pragma unroll
    for (int k = 0; k < CH; ++k) {
        wr[k] = Wr[k * CH + c];
        wn[k] = Wn[k * CH + c];
    }
    const float bc = bias[c];

    float2 rs2 = {0, 0}, mr2 = {0, 0};
    if constexpr (NORM) {
        float2 m2 = ((const float2*)meanp)[c * 2 + bh];
        rs2 = ((const float2*)rstdp)[c * 2 + bh];
        mr2 = make_float2(m2.x * rs2.x, m2.y * rs2.y);
    }

    const float2* __restrict__ h2 = (const float2*)hin;

    for (int n = wid; n < NC; n += NWAVES) {
        float2 xv = h2[(n * CH + c) * 2 + bh];
        int e0 = rowp[n], e1 = rowp[n + 1];
        float2 a0 = {0, 0}, a1 = {0, 0}, a2 = {0, 0}, a3 = {0, 0};
        float sw = 0.f;
        int e = e0;
        for (; e + 4 <= e1; e += 4) {
            int s0 = srcs[e], s1 = srcs[e + 1], s2 = srcs[e + 2], s3 = srcs[e + 3];
            float w0 = wts[e], w1 = wts[e + 1], w2 = wts[e + 2], w3 = wts[e + 3];
            float2 v0 = h2[(s0 * CH + c) * 2 + bh];
            float2 v1 = h2[(s1 * CH + c) * 2 + bh];
            float2 v2 = h2[(s2 * CH + c) * 2 + bh];
            float2 v3 = h2[(s3 * CH + c) * 2 + bh];
            a0.x += w0 * v0.x; a0.y += w0 * v0.y;
            a1.x += w1 * v1.x; a1.y += w1 * v1.y;
            a2.x += w2 * v2.x; a2.y += w2 * v2.y;
            a3.x += w3 * v3.x; a3.y += w3 * v3.y;
            if constexpr (NORM) sw += (w0 + w1) + (w2 + w3);
        }
        for (; e < e1; ++e) {
            float w0 = wts[e];
            float2 v0 = h2[(srcs[e] * CH + c) * 2 + bh];
            a0.x += w0 * v0.x; a0.y += w0 * v0.y;
            if constexpr (NORM) sw += w0;
        }
        float2 ag = make_float2((a0.x + a1.x) + (a2.x + a3.x),
                                (a0.y + a1.y) + (a2.y + a3.y));
        if constexpr (NORM) {
            xv.x = xv.x * rs2.x - mr2.x;       xv.y = xv.y * rs2.y - mr2.y;
            ag.x = ag.x * rs2.x - mr2.x * sw;  ag.y = ag.y * rs2.y - mr2.y * sw;
        }
        float2 acc = make_float2(bc, bc);
        MM<CH - 1>::run(xv, ag, wr, wn, acc);
        if constexpr (OUTBNC) {
            hout[(2 * bh + 0) * (NC * CH) + n * CH + c] = acc.x;
            hout[(2 * bh + 1) * (NC * CH) + n * CH + c] = acc.y;
        } else {
            ((float2*)hout)[(n * CH + c) * 2 + bh] = acc;
        }
    }
}

// ---------------- instance-norm stats over [N][CH][B] (float4 = 4 batches) ----
__global__ __launch_bounds__(256)
void stats_kernel(const float* __restrict__ h, float* __restrict__ st) {
    __shared__ float4 ls[256], lq[256];
    const int tid = threadIdx.x;
    float4 s = {0, 0, 0, 0}, q = {0, 0, 0, 0};
    const float4* __restrict__ h4 = (const float4*)h;
    const int total4 = NC * CH;
    const int stride = gridDim.x * blockDim.x;   // 200*256, %32==0 -> lane channel fixed
    for (int i = blockIdx.x * blockDim.x + tid; i < total4; i += stride) {
        float4 v = h4[i];
        s.x += v.x; s.y += v.y; s.z += v.z; s.w += v.w;
        q.x += v.x * v.x; q.y += v.y * v.y; q.z += v.z * v.z; q.w += v.w * v.w;
    }
    ls[tid] = s; lq[tid] = q;
    __syncthreads();
    if (tid < 32) {
        float4 ts = ls[tid], tq = lq[tid];
#pragma unroll
        for (int g = 1; g < 8; ++g) {
            float4 o = ls[g * 32 + tid];
            ts.x += o.x; ts.y += o.y; ts.z += o.z; ts.w += o.w;
            float4 p = lq[g * 32 + tid];
            tq.x += p.x; tq.y += p.y; tq.z += p.z; tq.w += p.w;
        }
        atomicAdd(&st[tid * 4 + 0], ts.x);
        atomicAdd(&st[tid * 4 + 1], ts.y);
        atomicAdd(&st[tid * 4 + 2], ts.z);
        atomicAdd(&st[tid * 4 + 3], ts.w);
        atomicAdd(&st[128 + tid * 4 + 0], tq.x);
        atomicAdd(&st[128 + tid * 4 + 1], tq.y);
        atomicAdd(&st[128 + tid * 4 + 2], tq.z);
        atomicAdd(&st[128 + tid * 4 + 3], tq.w);
    }
}

__global__ void stats_fin(float* __restrict__ st) {
    int i = threadIdx.x;
    if (i < 128) {
        float m = st[i] * (1.f / NC);
        float v = st[128 + i] * (1.f / NC) - m * m;
        st[256 + i] = m;                 // mean[c*4+b]
        st[384 + i] = rsqrtf(v + EPSV);  // rstd[c*4+b]
    }
}

extern "C" void kernel_launch(void* const* d_in, const int* in_sizes, int n_in,
                              void* d_out, int out_size, void* d_ws, size_t ws_size,
                              hipStream_t stream) {
    const float* x         = (const float*)d_in[0];
    const int*   pool_src  = (const int*)d_in[1];
    const int*   pool_dst  = (const int*)d_in[2];
    const float* pool_attr = (const float*)d_in[3];
    const int*   edge_src  = (const int*)d_in[4];
    const int*   edge_dst  = (const int*)d_in[5];
    const float* edge_attr = (const float*)d_in[6];
    const float* Wr1 = (const float*)d_in[8];
    const float* Wn1 = (const float*)d_in[9];
    const float* b1  = (const float*)d_in[10];
    const float* Wr2 = (const float*)d_in[11];
    const float* Wn2 = (const float*)d_in[12];
    const float* b2  = (const float*)d_in[13];
    const float* Wr3 = (const float*)d_in[14];
    const float* Wn3 = (const float*)d_in[15];
    const float* b3  = (const float*)d_in[16];
    const float* Wr4 = (const float*)d_in[17];
    const float* Wn4 = (const float*)d_in[18];
    const float* b4  = (const float*)d_in[19];

    // ---- workspace layout (~34 MB) ----
    char* w = (char*)d_ws;
    float* bufA    = (float*)w;   w += (size_t)NC * CH * BB * 4;     // 25.6 MB
    int*   poolRow = (int*)w;     w += (size_t)(NC + 1) * 4;
    int*   edgeRow = (int*)w;     w += (size_t)(NC + 1) * 4;
    int*   zbase   = (int*)w;                                        // contiguous zero region:
    int*   poolNext= (int*)w;     w += (size_t)NC * 4;
    int*   edgeNext= (int*)w;     w += (size_t)NC * 4;
    float* stats   = (float*)w;   w += 512 * 4;   // s[128] q[128] mean[128] rstd[128]
    int*   poolS   = (int*)w;     w += (size_t)NPOOL * 4;
    float* poolW   = (float*)w;   w += (size_t)NPOOL * 4;
    int*   edgeS   = (int*)w;     w += (size_t)NEDGE * 4;
    float* edgeW   = (float*)w;   w += (size_t)NEDGE * 4;

    float* po = (float*)d_out;    // d_out doubles as [N][CH][B] scratch until final pass

    const int ZN = NC + NC + 256; // poolNext + edgeNext + stats sums/sq

    // ---- CSR build (by dst; reused by all 4 convs) ----
    zero_kernel<<<98, 1024, 0, stream>>>(zbase, ZN);
    hist_kernel<<<782, 256, 0, stream>>>(pool_dst, NPOOL, poolNext);
    hist_kernel<<<3125, 256, 0, stream>>>(edge_dst, NEDGE, edgeNext);
    scan_kernel<<<1, 1024, 0, stream>>>(poolNext, poolRow, NC);
    scan_kernel<<<1, 1024, 0, stream>>>(edgeNext, edgeRow, NC);
    scatter_kernel<<<782, 256, 0, stream>>>(pool_src, pool_dst, pool_attr, NPOOL,
                                            poolNext, poolS, poolW);
    scatter_kernel<<<3125, 256, 0, stream>>>(edge_src, edge_dst, edge_attr, NEDGE,
                                             edgeNext, edgeS, edgeW);

    // ---- pipeline (ping-pong between d_out memory and bufA) ----
    pool_kernel<<<2048, 256, 0, stream>>>(x, po, poolRow, poolS, poolW);
    gconv_kernel<false, false><<<2048, 256, 0, stream>>>(po, bufA, edgeRow, edgeS, edgeW,
                                                         Wr1, Wn1, b1, nullptr, nullptr);
    gconv_kernel<false, false><<<2048, 256, 0, stream>>>(bufA, po, edgeRow, edgeS, edgeW,
                                                         Wr2, Wn2, b2, nullptr, nullptr);
    stats_kernel<<<200, 256, 0, stream>>>(po, stats);
    stats_fin<<<1, 128, 0, stream>>>(stats);
    gconv_kernel<true, false><<<2048, 256, 0, stream>>>(po, bufA, edgeRow, edgeS, edgeW,
                                                        Wr3, Wn3, b3, stats + 256, stats + 384);
    gconv_kernel<false, true><<<2048, 256, 0, stream>>>(bufA, po, edgeRow, edgeS, edgeW,
                                                        Wr4, Wn4, b4, nullptr, nullptr);
}

// Round 4
// 866.615 us; speedup vs baseline: 1.2880x; 1.1615x over previous
//
#include <hip/hip_runtime.h>

#define BB 4
#define NFINE 200000
#define NC 50000
#define CH 32
#define NPOOL 200000
#define NEDGE 800000
#define EPSV 1e-5f
#define NWAVES 8192   // 2048 blocks * 4 waves/block (grid-stride kernels)

__device__ __forceinline__ int rfl(int v) { return __builtin_amdgcn_readfirstlane(v); }

// ---------------- zero ----------------
__global__ void zero_kernel(int* __restrict__ p, int n) {
    int i = blockIdx.x * blockDim.x + threadIdx.x;
    int stride = gridDim.x * blockDim.x;
    for (; i < n; i += stride) p[i] = 0;
}

// ---------------- histogram ----------------
__global__ void hist_kernel(const int* __restrict__ dst, int n, int* __restrict__ cnt) {
    int i = blockIdx.x * blockDim.x + threadIdx.x;
    int stride = gridDim.x * blockDim.x;
    for (; i < n; i += stride) atomicAdd(&cnt[dst[i]], 1);
}

// ---------------- single-block exclusive scan ----------------
__global__ __launch_bounds__(1024)
void scan_kernel(int* __restrict__ cnt_next, int* __restrict__ rowp, int n) {
    __shared__ int lds[1024];
    int t = threadIdx.x;
    int chunk = (n + 1023) / 1024;
    int s = t * chunk;
    int e = min(s + chunk, n);
    int sum = 0;
    for (int i = s; i < e; ++i) sum += cnt_next[i];
    lds[t] = sum;
    __syncthreads();
    for (int off = 1; off < 1024; off <<= 1) {
        int v = (t >= off) ? lds[t - off] : 0;
        __syncthreads();
        lds[t] += v;
        __syncthreads();
    }
    int base = lds[t] - sum;
    for (int i = s; i < e; ++i) {
        int cv = cnt_next[i];
        rowp[i] = base;
        cnt_next[i] = base;
        base += cv;
    }
    if (t == 1023) rowp[n] = lds[1023];
}

// ---------------- scatter into CSR (packed src+weight, one 8B store/edge) ----
__global__ void scatter_kernel(const int* __restrict__ src, const int* __restrict__ dst,
                               const float* __restrict__ attr, int n,
                               int* __restrict__ next, int2* __restrict__ pk) {
    int i = blockIdx.x * blockDim.x + threadIdx.x;
    int stride = gridDim.x * blockDim.x;
    for (; i < n; i += stride) {
        int d = dst[i];
        int pos = atomicAdd(&next[d], 1);
        pk[pos] = make_int2(src[i], __float_as_int(attr[i]));
    }
}

// ---------------- pool: x[B][NF][CH] -> pooled[N][CH][B]; 1 node per wave ----
__global__ __launch_bounds__(256)
void pool_kernel(const float* __restrict__ x, float* __restrict__ pooled,
                 const int* __restrict__ rowp, const int2* __restrict__ pk) {
    const int tid = threadIdx.x;
    const int lane = tid & 63;
    const int c = lane & 31;
    const int bh = lane >> 5;
    const int n = blockIdx.x * 4 + (tid >> 6);
    if (n >= NC) return;
    const float* __restrict__ xA = x + (size_t)(2 * bh) * NFINE * CH;
    const float* __restrict__ xB = x + (size_t)(2 * bh + 1) * NFINE * CH;
    int e0 = rfl(rowp[n]), e1 = rfl(rowp[n + 1]);
    float2 a0 = {0, 0}, a1 = {0, 0}, a2 = {0, 0}, a3 = {0, 0};
    int e = e0;
    for (; e + 4 <= e1; e += 4) {
        int2 p0 = pk[e], p1 = pk[e + 1], p2 = pk[e + 2], p3 = pk[e + 3];
        float w0 = __int_as_float(p0.y), w1 = __int_as_float(p1.y);
        float w2 = __int_as_float(p2.y), w3 = __int_as_float(p3.y);
        a0.x += w0 * xA[p0.x * CH + c]; a0.y += w0 * xB[p0.x * CH + c];
        a1.x += w1 * xA[p1.x * CH + c]; a1.y += w1 * xB[p1.x * CH + c];
        a2.x += w2 * xA[p2.x * CH + c]; a2.y += w2 * xB[p2.x * CH + c];
        a3.x += w3 * xA[p3.x * CH + c]; a3.y += w3 * xB[p3.x * CH + c];
    }
    for (; e < e1; ++e) {
        int2 p0 = pk[e];
        float w0 = __int_as_float(p0.y);
        a0.x += w0 * xA[p0.x * CH + c];
        a0.y += w0 * xB[p0.x * CH + c];
    }
    ((float2*)pooled)[(n * CH + c) * 2 + bh] =
        make_float2((a0.x + a1.x) + (a2.x + a3.x), (a0.y + a1.y) + (a2.y + a3.y));
}

// ---------------- dense pass: z = (norm?)h@Wr + b (in-place), g = (norm?)h@Wn ----
// Per-wave LDS staging broadcasts the node row; weights live in 64 VGPRs.
template<bool NORM>
__global__ __launch_bounds__(256)
void dense_kernel(const float* hin, float* zout /*aliases hin*/, float* __restrict__ gout,
                  const float* __restrict__ Wr, const float* __restrict__ Wn,
                  const float* __restrict__ bias, const float* __restrict__ st) {
    __shared__ float2 stage[4][2][64];
    const int tid = threadIdx.x;
    const int lane = tid & 63;
    const int c = lane & 31;
    const int bh = lane >> 5;
    const int w = tid >> 6;
    const int wid = blockIdx.x * 4 + w;

    float wr[CH], wn[CH];
#pragma unroll
    for (int k = 0; k < CH; ++k) {
        wr[k] = Wr[k * CH + c];
        wn[k] = Wn[k * CH + c];
    }
    const float bc = bias[c];

    float2 rs = {1.f, 1.f}, mr = {0.f, 0.f};
    if constexpr (NORM) {
        float2 m2 = ((const float2*)(st + 256))[c * 2 + bh];
        rs = ((const float2*)(st + 384))[c * 2 + bh];
        mr = make_float2(m2.x * rs.x, m2.y * rs.y);
    }

    const float2* h2 = (const float2*)hin;
    int it = 0;
    for (int n = wid; n < NC; n += NWAVES, ++it) {
        float2 xv = h2[(n * CH + c) * 2 + bh];
        if constexpr (NORM) {
            xv.x = xv.x * rs.x - mr.x;
            xv.y = xv.y * rs.y - mr.y;
        }
        stage[w][it & 1][lane] = xv;
        float2 z = {bc, bc}, g = {0.f, 0.f};
#pragma unroll
        for (int k = 0; k < CH; ++k) {
            float2 v = stage[w][it & 1][bh * 32 + k];
            z.x += v.x * wr[k]; z.y += v.y * wr[k];
            g.x += v.x * wn[k]; g.y += v.y * wn[k];
        }
        ((float2*)zout)[(n * CH + c) * 2 + bh] = z;
        ((float2*)gout)[(n * CH + c) * 2 + bh] = g;
    }
}

// ---------------- gather pass: out[n] = z[n] + sum_e w_e * g[src_e] ----------
// 1 node per wave; scalar-pipe index loads; 8 gathers in flight.
template<bool OUTBNC>
__global__ __launch_bounds__(256)
void gather_kernel(const float* zin /*aliases hout when !OUTBNC*/,
                   const float* __restrict__ gin, float* hout,
                   const int* __restrict__ rowp, const int2* __restrict__ pk) {
    const int tid = threadIdx.x;
    const int lane = tid & 63;
    const int c = lane & 31;
    const int bh = lane >> 5;
    const int n = blockIdx.x * 4 + (tid >> 6);
    if (n >= NC) return;

    const float2* __restrict__ g2 = (const float2*)gin;
    float2 acc = ((const float2*)zin)[(n * CH + c) * 2 + bh];
    float2 ac1 = {0.f, 0.f};
    int e0 = rfl(rowp[n]), e1 = rfl(rowp[n + 1]);
    int e = e0;
    for (; e + 8 <= e1; e += 8) {
#pragma unroll
        for (int i = 0; i < 8; i += 2) {
            int2 p0 = pk[e + i], p1 = pk[e + i + 1];
            float w0 = __int_as_float(p0.y), w1 = __int_as_float(p1.y);
            float2 v0 = g2[(p0.x * CH + c) * 2 + bh];
            float2 v1 = g2[(p1.x * CH + c) * 2 + bh];
            acc.x += w0 * v0.x; acc.y += w0 * v0.y;
            ac1.x += w1 * v1.x; ac1.y += w1 * v1.y;
        }
    }
    for (; e < e1; ++e) {
        int2 p0 = pk[e];
        float w0 = __int_as_float(p0.y);
        float2 v0 = g2[(p0.x * CH + c) * 2 + bh];
        acc.x += w0 * v0.x; acc.y += w0 * v0.y;
    }
    acc.x += ac1.x; acc.y += ac1.y;
    if constexpr (OUTBNC) {
        hout[(size_t)(2 * bh + 0) * (NC * CH) + n * CH + c] = acc.x;
        hout[(size_t)(2 * bh + 1) * (NC * CH) + n * CH + c] = acc.y;
    } else {
        ((float2*)hout)[(n * CH + c) * 2 + bh] = acc;
    }
}

// ---------------- instance-norm stats over [N][CH][B] (float4 = 4 batches) ----
__global__ __launch_bounds__(256)
void stats_kernel(const float* __restrict__ h, float* __restrict__ st) {
    __shared__ float4 ls[256], lq[256];
    const int tid = threadIdx.x;
    float4 s = {0, 0, 0, 0}, q = {0, 0, 0, 0};
    const float4* __restrict__ h4 = (const float4*)h;
    const int total4 = NC * CH;
    const int stride = gridDim.x * blockDim.x;
    for (int i = blockIdx.x * blockDim.x + tid; i < total4; i += stride) {
        float4 v = h4[i];
        s.x += v.x; s.y += v.y; s.z += v.z; s.w += v.w;
        q.x += v.x * v.x; q.y += v.y * v.y; q.z += v.z * v.z; q.w += v.w * v.w;
    }
    ls[tid] = s; lq[tid] = q;
    __syncthreads();
    if (tid < 32) {
        float4 ts = ls[tid], tq = lq[tid];
#pragma unroll
        for (int g = 1; g < 8; ++g) {
            float4 o = ls[g * 32 + tid];
            ts.x += o.x; ts.y += o.y; ts.z += o.z; ts.w += o.w;
            float4 p = lq[g * 32 + tid];
            tq.x += p.x; tq.y += p.y; tq.z += p.z; tq.w += p.w;
        }
        atomicAdd(&st[tid * 4 + 0], ts.x);
        atomicAdd(&st[tid * 4 + 1], ts.y);
        atomicAdd(&st[tid * 4 + 2], ts.z);
        atomicAdd(&st[tid * 4 + 3], ts.w);
        atomicAdd(&st[128 + tid * 4 + 0], tq.x);
        atomicAdd(&st[128 + tid * 4 + 1], tq.y);
        atomicAdd(&st[128 + tid * 4 + 2], tq.z);
        atomicAdd(&st[128 + tid * 4 + 3], tq.w);
    }
}

__global__ void stats_fin(float* __restrict__ st) {
    int i = threadIdx.x;
    if (i < 128) {
        float m = st[i] * (1.f / NC);
        float v = st[128 + i] * (1.f / NC) - m * m;
        st[256 + i] = m;
        st[384 + i] = rsqrtf(v + EPSV);
    }
}

// ---------------- transpose NCB -> BNC (small-ws path bounce) ----------------
__global__ __launch_bounds__(256)
void transpose_kernel(const float* __restrict__ in, float* __restrict__ out) {
    const int tid = threadIdx.x;
    const int lane = tid & 63;
    const int c = lane & 31;
    const int bh = lane >> 5;
    const int n = blockIdx.x * 4 + (tid >> 6);
    if (n >= NC) return;
    float2 v = ((const float2*)in)[(n * CH + c) * 2 + bh];
    out[(size_t)(2 * bh + 0) * (NC * CH) + n * CH + c] = v.x;
    out[(size_t)(2 * bh + 1) * (NC * CH) + n * CH + c] = v.y;
}

extern "C" void kernel_launch(void* const* d_in, const int* in_sizes, int n_in,
                              void* d_out, int out_size, void* d_ws, size_t ws_size,
                              hipStream_t stream) {
    const float* x         = (const float*)d_in[0];
    const int*   pool_src  = (const int*)d_in[1];
    const int*   pool_dst  = (const int*)d_in[2];
    const float* pool_attr = (const float*)d_in[3];
    const int*   edge_src  = (const int*)d_in[4];
    const int*   edge_dst  = (const int*)d_in[5];
    const float* edge_attr = (const float*)d_in[6];
    const float* Wr1 = (const float*)d_in[8];
    const float* Wn1 = (const float*)d_in[9];
    const float* b1  = (const float*)d_in[10];
    const float* Wr2 = (const float*)d_in[11];
    const float* Wn2 = (const float*)d_in[12];
    const float* b2  = (const float*)d_in[13];
    const float* Wr3 = (const float*)d_in[14];
    const float* Wn3 = (const float*)d_in[15];
    const float* b3  = (const float*)d_in[16];
    const float* Wr4 = (const float*)d_in[17];
    const float* Wn4 = (const float*)d_in[18];
    const float* b4  = (const float*)d_in[19];

    const size_t BUFB = (size_t)NC * CH * BB * 4;   // 25,600,000 B
    const size_t CSRB = 2 * (size_t)(NC + 1) * 4 + 2 * (size_t)NC * 4 + 512 * 4
                        + (size_t)NPOOL * 8 + (size_t)NEDGE * 8;  // ~8.8 MB
    char* w = (char*)d_ws;
    float* G = (float*)w;  w += BUFB;
    const bool bigws = ws_size >= 2 * BUFB + CSRB + 1024;
    float* P;
    if (bigws) { P = (float*)w; w += BUFB; }
    else       { P = (float*)d_out; }
    int*   poolRow  = (int*)w;  w += (size_t)(NC + 1) * 4;
    int*   edgeRow  = (int*)w;  w += (size_t)(NC + 1) * 4;
    int*   zbase    = (int*)w;                       // contiguous zero region:
    int*   poolNext = (int*)w;  w += (size_t)NC * 4;
    int*   edgeNext = (int*)w;  w += (size_t)NC * 4;
    float* stats    = (float*)w; w += 512 * 4;
    int2*  poolPk   = (int2*)w; w += (size_t)NPOOL * 8;
    int2*  edgePk   = (int2*)w; w += (size_t)NEDGE * 8;

    float* out = (float*)d_out;
    const int ZN = NC + NC + 256;      // next cursors + stats sums/sumsq
    const int NB = (NC + 3) / 4;       // 12500 blocks, 1 node/wave

    // ---- CSR build (by dst; reused by all 4 convs) ----
    zero_kernel<<<98, 1024, 0, stream>>>(zbase, ZN);
    hist_kernel<<<782, 256, 0, stream>>>(pool_dst, NPOOL, poolNext);
    hist_kernel<<<3125, 256, 0, stream>>>(edge_dst, NEDGE, edgeNext);
    scan_kernel<<<1, 1024, 0, stream>>>(poolNext, poolRow, NC);
    scan_kernel<<<1, 1024, 0, stream>>>(edgeNext, edgeRow, NC);
    scatter_kernel<<<782, 256, 0, stream>>>(pool_src, pool_dst, pool_attr, NPOOL,
                                            poolNext, poolPk);
    scatter_kernel<<<3125, 256, 0, stream>>>(edge_src, edge_dst, edge_attr, NEDGE,
                                             edgeNext, edgePk);

    // ---- pipeline: each conv = dense (z in-place over h, g -> G) + gather (in-place) ----
    pool_kernel<<<NB, 256, 0, stream>>>(x, P, poolRow, poolPk);

    dense_kernel<false><<<2048, 256, 0, stream>>>(P, P, G, Wr1, Wn1, b1, nullptr);
    gather_kernel<false><<<NB, 256, 0, stream>>>(P, G, P, edgeRow, edgePk);

    dense_kernel<false><<<2048, 256, 0, stream>>>(P, P, G, Wr2, Wn2, b2, nullptr);
    gather_kernel<false><<<NB, 256, 0, stream>>>(P, G, P, edgeRow, edgePk);

    stats_kernel<<<200, 256, 0, stream>>>(P, stats);
    stats_fin<<<1, 128, 0, stream>>>(stats);

    dense_kernel<true><<<2048, 256, 0, stream>>>(P, P, G, Wr3, Wn3, b3, stats);
    gather_kernel<false><<<NB, 256, 0, stream>>>(P, G, P, edgeRow, edgePk);

    dense_kernel<false><<<2048, 256, 0, stream>>>(P, P, G, Wr4, Wn4, b4, nullptr);
    if (bigws) {
        gather_kernel<true><<<NB, 256, 0, stream>>>(P, G, out, edgeRow, edgePk);
    } else {
        gather_kernel<false><<<NB, 256, 0, stream>>>(P, G, P, edgeRow, edgePk);
        transpose_kernel<<<NB, 256, 0, stream>>>(P, G);   // P==d_out (NCB) -> G (BNC)
        hipMemcpyAsync(out, G, BUFB, hipMemcpyDeviceToDevice, stream);
    }
}

// Round 7
// 674.649 us; speedup vs baseline: 1.6545x; 1.2845x over previous
//
#include <hip/hip_runtime.h>

#define BB 4
#define NFINE 200000
#define NC 50000
#define CH 32
#define NPOOL 200000
#define NEDGE 800000
#define EPSV 1e-5f
#define NWAVES 8192   // 2048 blocks * 4 waves/block (grid-stride kernels)
#define NCHUNK 49     // ceil(NC / 1024)

__device__ __forceinline__ int rfl(int v) { return __builtin_amdgcn_readfirstlane(v); }

// ---------------- zero ----------------
__global__ void zero_kernel(int* __restrict__ p, int n) {
    int i = blockIdx.x * blockDim.x + threadIdx.x;
    int stride = gridDim.x * blockDim.x;
    for (; i < n; i += stride) p[i] = 0;
}

// ---------------- histogram ----------------
__global__ void hist_kernel(const int* __restrict__ dst, int n, int* __restrict__ cnt) {
    int i = blockIdx.x * blockDim.x + threadIdx.x;
    int stride = gridDim.x * blockDim.x;
    for (; i < n; i += stride) atomicAdd(&cnt[dst[i]], 1);
}

// ---------------- device-wide exclusive scan, phase 1: per-chunk sums ------
// grid (NCHUNK, 2): y=0 pool counters, y=1 edge counters.
__global__ __launch_bounds__(1024)
void chunk_sum_kernel(const int* __restrict__ cntP, const int* __restrict__ cntE,
                      int* __restrict__ scanTmp) {
    __shared__ int lds[1024];
    const int* __restrict__ cnt = blockIdx.y ? cntE : cntP;
    int* csum = scanTmp + (blockIdx.y ? 64 : 0);
    const int j = blockIdx.x, t = threadIdx.x;
    const int idx = j * 1024 + t;
    lds[t] = (idx < NC) ? cnt[idx] : 0;
    __syncthreads();
    for (int off = 512; off > 0; off >>= 1) {
        if (t < off) lds[t] += lds[t + off];
        __syncthreads();
    }
    if (t == 0) csum[j] = lds[0];
}

// ---------------- phase 2: scan the NCHUNK chunk sums (one wave) ------------
__global__ void chunk_mid_kernel(int* __restrict__ scanTmp) {
    int* csum = scanTmp + (blockIdx.y ? 64 : 0);
    int* coff = scanTmp + (blockIdx.y ? 192 : 128);
    const int t = threadIdx.x;
    int v = (t < NCHUNK) ? csum[t] : 0;
    const int orig = v;
    for (int off = 1; off < 64; off <<= 1) {
        int u = __shfl_up(v, off, 64);
        if (t >= off) v += u;
    }
    if (t < NCHUNK) coff[t] = v - orig;   // exclusive chunk offset
}

// ---------------- phase 3: block scan within chunk + chunk offset -----------
// Writes rowp[idx] and resets the counter (in place) to the exclusive prefix
// so it can serve as the scatter cursor. Also writes rowp[NC] (total).
__global__ __launch_bounds__(1024)
void chunk_scan_kernel(int* __restrict__ cntP, int* __restrict__ cntE,
                       const int* __restrict__ scanTmp,
                       int* __restrict__ rowpP, int* __restrict__ rowpE) {
    __shared__ int lds[1024];
    int* __restrict__ cnt = blockIdx.y ? cntE : cntP;
    const int* coff = scanTmp + (blockIdx.y ? 192 : 128);
    int* __restrict__ rowp = blockIdx.y ? rowpE : rowpP;
    const int j = blockIdx.x, t = threadIdx.x;
    const int idx = j * 1024 + t;
    const int v = (idx < NC) ? cnt[idx] : 0;
    lds[t] = v;
    __syncthreads();
    for (int off = 1; off < 1024; off <<= 1) {
        int u = (t >= off) ? lds[t - off] : 0;
        __syncthreads();
        lds[t] += u;
        __syncthreads();
    }
    const int excl = lds[t] - v + coff[j];
    if (idx < NC) {
        rowp[idx] = excl;
        cnt[idx] = excl;        // scatter cursor
    }
    if (idx == NC - 1) rowp[NC] = excl + v;
}

// ---------------- scatter into CSR (packed src+weight, one 8B store/edge) ----
__global__ void scatter_kernel(const int* __restrict__ src, const int* __restrict__ dst,
                               const float* __restrict__ attr, int n,
                               int* __restrict__ next, int2* __restrict__ pk) {
    int i = blockIdx.x * blockDim.x + threadIdx.x;
    int stride = gridDim.x * blockDim.x;
    for (; i < n; i += stride) {
        int d = dst[i];
        int pos = atomicAdd(&next[d], 1);
        pk[pos] = make_int2(src[i], __float_as_int(attr[i]));
    }
}

// ---------------- pool: x[B][NF][CH] -> pooled[N][CH][B]; 1 node per wave ----
__global__ __launch_bounds__(256)
void pool_kernel(const float* __restrict__ x, float* __restrict__ pooled,
                 const int* __restrict__ rowp, const int2* __restrict__ pk) {
    const int tid = threadIdx.x;
    const int lane = tid & 63;
    const int c = lane & 31;
    const int bh = lane >> 5;
    const int n = blockIdx.x * 4 + (tid >> 6);
    if (n >= NC) return;
    const float* __restrict__ xA = x + (size_t)(2 * bh) * NFINE * CH;
    const float* __restrict__ xB = x + (size_t)(2 * bh + 1) * NFINE * CH;
    int e0 = rfl(rowp[n]), e1 = rfl(rowp[n + 1]);
    float2 a0 = {0, 0}, a1 = {0, 0}, a2 = {0, 0}, a3 = {0, 0};
    int e = e0;
    for (; e + 4 <= e1; e += 4) {
        int2 p0 = pk[e], p1 = pk[e + 1], p2 = pk[e + 2], p3 = pk[e + 3];
        float w0 = __int_as_float(p0.y), w1 = __int_as_float(p1.y);
        float w2 = __int_as_float(p2.y), w3 = __int_as_float(p3.y);
        a0.x += w0 * xA[p0.x * CH + c]; a0.y += w0 * xB[p0.x * CH + c];
        a1.x += w1 * xA[p1.x * CH + c]; a1.y += w1 * xB[p1.x * CH + c];
        a2.x += w2 * xA[p2.x * CH + c]; a2.y += w2 * xB[p2.x * CH + c];
        a3.x += w3 * xA[p3.x * CH + c]; a3.y += w3 * xB[p3.x * CH + c];
    }
    for (; e < e1; ++e) {
        int2 p0 = pk[e];
        float w0 = __int_as_float(p0.y);
        a0.x += w0 * xA[p0.x * CH + c];
        a0.y += w0 * xB[p0.x * CH + c];
    }
    ((float2*)pooled)[(n * CH + c) * 2 + bh] =
        make_float2((a0.x + a1.x) + (a2.x + a3.x), (a0.y + a1.y) + (a2.y + a3.y));
}

// ---------------- dense pass: z = (norm?)h@Wr + b (in-place), g = (norm?)h@Wn ----
template<bool NORM>
__global__ __launch_bounds__(256)
void dense_kernel(const float* hin, float* zout /*aliases hin*/, float* __restrict__ gout,
                  const float* __restrict__ Wr, const float* __restrict__ Wn,
                  const float* __restrict__ bias, const float* __restrict__ st) {
    __shared__ float2 stage[4][2][64];
    const int tid = threadIdx.x;
    const int lane = tid & 63;
    const int c = lane & 31;
    const int bh = lane >> 5;
    const int w = tid >> 6;
    const int wid = blockIdx.x * 4 + w;

    float wr[CH], wn[CH];
#pragma unroll
    for (int k = 0; k < CH; ++k) {
        wr[k] = Wr[k * CH + c];
        wn[k] = Wn[k * CH + c];
    }
    const float bc = bias[c];

    float2 rs = {1.f, 1.f}, mr = {0.f, 0.f};
    if constexpr (NORM) {
        float2 m2 = ((const float2*)(st + 256))[c * 2 + bh];
        rs = ((const float2*)(st + 384))[c * 2 + bh];
        mr = make_float2(m2.x * rs.x, m2.y * rs.y);
    }

    const float2* h2 = (const float2*)hin;
    int it = 0;
    for (int n = wid; n < NC; n += NWAVES, ++it) {
        float2 xv = h2[(n * CH + c) * 2 + bh];
        if constexpr (NORM) {
            xv.x = xv.x * rs.x - mr.x;
            xv.y = xv.y * rs.y - mr.y;
        }
        stage[w][it & 1][lane] = xv;
        float2 z = {bc, bc}, g = {0.f, 0.f};
#pragma unroll
        for (int k = 0; k < CH; ++k) {
            float2 v = stage[w][it & 1][bh * 32 + k];
            z.x += v.x * wr[k]; z.y += v.y * wr[k];
            g.x += v.x * wn[k]; g.y += v.y * wn[k];
        }
        ((float2*)zout)[(n * CH + c) * 2 + bh] = z;
        ((float2*)gout)[(n * CH + c) * 2 + bh] = g;
    }
}

// ---------------- gather pass: out[n] = z[n] + sum_e w_e * g[src_e] ----------
template<bool OUTBNC>
__global__ __launch_bounds__(256)
void gather_kernel(const float* zin /*aliases hout when !OUTBNC*/,
                   const float* __restrict__ gin, float* hout,
                   const int* __restrict__ rowp, const int2* __restrict__ pk) {
    const int tid = threadIdx.x;
    const int lane = tid & 63;
    const int c = lane & 31;
    const int bh = lane >> 5;
    const int n = blockIdx.x * 4 + (tid >> 6);
    if (n >= NC) return;

    const float2* __restrict__ g2 = (const float2*)gin;
    float2 acc = ((const float2*)zin)[(n * CH + c) * 2 + bh];
    float2 ac1 = {0.f, 0.f};
    int e0 = rfl(rowp[n]), e1 = rfl(rowp[n + 1]);
    int e = e0;
    for (; e + 8 <= e1; e += 8) {
#pragma unroll
        for (int i = 0; i < 8; i += 2) {
            int2 p0 = pk[e + i], p1 = pk[e + i + 1];
            float w0 = __int_as_float(p0.y), w1 = __int_as_float(p1.y);
            float2 v0 = g2[(p0.x * CH + c) * 2 + bh];
            float2 v1 = g2[(p1.x * CH + c) * 2 + bh];
            acc.x += w0 * v0.x; acc.y += w0 * v0.y;
            ac1.x += w1 * v1.x; ac1.y += w1 * v1.y;
        }
    }
    for (; e < e1; ++e) {
        int2 p0 = pk[e];
        float w0 = __int_as_float(p0.y);
        float2 v0 = g2[(p0.x * CH + c) * 2 + bh];
        acc.x += w0 * v0.x; acc.y += w0 * v0.y;
    }
    acc.x += ac1.x; acc.y += ac1.y;
    if constexpr (OUTBNC) {
        hout[(size_t)(2 * bh + 0) * (NC * CH) + n * CH + c] = acc.x;
        hout[(size_t)(2 * bh + 1) * (NC * CH) + n * CH + c] = acc.y;
    } else {
        ((float2*)hout)[(n * CH + c) * 2 + bh] = acc;
    }
}

// ---------------- instance-norm stats over [N][CH][B] (float4 = 4 batches) ----
__global__ __launch_bounds__(256)
void stats_kernel(const float* __restrict__ h, float* __restrict__ st) {
    __shared__ float4 ls[256], lq[256];
    const int tid = threadIdx.x;
    float4 s = {0, 0, 0, 0}, q = {0, 0, 0, 0};
    const float4* __restrict__ h4 = (const float4*)h;
    const int total4 = NC * CH;
    const int stride = gridDim.x * blockDim.x;
    for (int i = blockIdx.x * blockDim.x + tid; i < total4; i += stride) {
        float4 v = h4[i];
        s.x += v.x; s.y += v.y; s.z += v.z; s.w += v.w;
        q.x += v.x * v.x; q.y += v.y * v.y; q.z += v.z * v.z; q.w += v.w * v.w;
    }
    ls[tid] = s; lq[tid] = q;
    __syncthreads();
    if (tid < 32) {
        float4 ts = ls[tid], tq = lq[tid];
#pragma unroll
        for (int g = 1; g < 8; ++g) {
            float4 o = ls[g * 32 + tid];
            ts.x += o.x; ts.y += o.y; ts.z += o.z; ts.w += o.w;
            float4 p = lq[g * 32 + tid];
            tq.x += p.x; tq.y += p.y; tq.z += p.z; tq.w += p.w;
        }
        atomicAdd(&st[tid * 4 + 0], ts.x);
        atomicAdd(&st[tid * 4 + 1], ts.y);
        atomicAdd(&st[tid * 4 + 2], ts.z);
        atomicAdd(&st[tid * 4 + 3], ts.w);
        atomicAdd(&st[128 + tid * 4 + 0], tq.x);
        atomicAdd(&st[128 + tid * 4 + 1], tq.y);
        atomicAdd(&st[128 + tid * 4 + 2], tq.z);
        atomicAdd(&st[128 + tid * 4 + 3], tq.w);
    }
}

__global__ void stats_fin(float* __restrict__ st) {
    int i = threadIdx.x;
    if (i < 128) {
        float m = st[i] * (1.f / NC);
        float v = st[128 + i] * (1.f / NC) - m * m;
        st[256 + i] = m;
        st[384 + i] = rsqrtf(v + EPSV);
    }
}

// ---------------- transpose NCB -> BNC (small-ws path bounce) ----------------
__global__ __launch_bounds__(256)
void transpose_kernel(const float* __restrict__ in, float* __restrict__ out) {
    const int tid = threadIdx.x;
    const int lane = tid & 63;
    const int c = lane & 31;
    const int bh = lane >> 5;
    const int n = blockIdx.x * 4 + (tid >> 6);
    if (n >= NC) return;
    float2 v = ((const float2*)in)[(n * CH + c) * 2 + bh];
    out[(size_t)(2 * bh + 0) * (NC * CH) + n * CH + c] = v.x;
    out[(size_t)(2 * bh + 1) * (NC * CH) + n * CH + c] = v.y;
}

extern "C" void kernel_launch(void* const* d_in, const int* in_sizes, int n_in,
                              void* d_out, int out_size, void* d_ws, size_t ws_size,
                              hipStream_t stream) {
    const float* x         = (const float*)d_in[0];
    const int*   pool_src  = (const int*)d_in[1];
    const int*   pool_dst  = (const int*)d_in[2];
    const float* pool_attr = (const float*)d_in[3];
    const int*   edge_src  = (const int*)d_in[4];
    const int*   edge_dst  = (const int*)d_in[5];
    const float* edge_attr = (const float*)d_in[6];
    const float* Wr1 = (const float*)d_in[8];
    const float* Wn1 = (const float*)d_in[9];
    const float* b1  = (const float*)d_in[10];
    const float* Wr2 = (const float*)d_in[11];
    const float* Wn2 = (const float*)d_in[12];
    const float* b2  = (const float*)d_in[13];
    const float* Wr3 = (const float*)d_in[14];
    const float* Wn3 = (const float*)d_in[15];
    const float* b3  = (const float*)d_in[16];
    const float* Wr4 = (const float*)d_in[17];
    const float* Wn4 = (const float*)d_in[18];
    const float* b4  = (const float*)d_in[19];

    const size_t BUFB = (size_t)NC * CH * BB * 4;   // 25,600,000 B
    const size_t CSRB = 2 * (size_t)(NC + 1) * 4 + 2 * (size_t)NC * 4 + 512 * 4 + 256 * 4
                        + (size_t)NPOOL * 8 + (size_t)NEDGE * 8;  // ~8.8 MB
    char* w = (char*)d_ws;
    float* G = (float*)w;  w += BUFB;
    const bool bigws = ws_size >= 2 * BUFB + CSRB + 1024;
    float* P;
    if (bigws) { P = (float*)w; w += BUFB; }
    else       { P = (float*)d_out; }
    int*   poolRow  = (int*)w;  w += (size_t)(NC + 1) * 4;
    int*   edgeRow  = (int*)w;  w += (size_t)(NC + 1) * 4;
    int*   zbase    = (int*)w;                       // contiguous zero region:
    int*   poolNext = (int*)w;  w += (size_t)NC * 4;
    int*   edgeNext = (int*)w;  w += (size_t)NC * 4;
    float* stats    = (float*)w; w += 512 * 4;
    int*   scanTmp  = (int*)w;  w += 256 * 4;       // csumP|csumE|coffP|coffE (64 each)
    int2*  poolPk   = (int2*)w; w += (size_t)NPOOL * 8;
    int2*  edgePk   = (int2*)w; w += (size_t)NEDGE * 8;

    float* out = (float*)d_out;
    const int ZN = NC + NC + 256;      // next cursors + stats sums/sumsq
    const int NB = (NC + 3) / 4;       // 12500 blocks, 1 node/wave

    // ---- CSR build (by dst; reused by all 4 convs) ----
    zero_kernel<<<98, 1024, 0, stream>>>(zbase, ZN);
    hist_kernel<<<782, 256, 0, stream>>>(pool_dst, NPOOL, poolNext);
    hist_kernel<<<3125, 256, 0, stream>>>(edge_dst, NEDGE, edgeNext);
    chunk_sum_kernel<<<dim3(NCHUNK, 2), 1024, 0, stream>>>(poolNext, edgeNext, scanTmp);
    chunk_mid_kernel<<<dim3(1, 2), 64, 0, stream>>>(scanTmp);
    chunk_scan_kernel<<<dim3(NCHUNK, 2), 1024, 0, stream>>>(poolNext, edgeNext, scanTmp,
                                                            poolRow, edgeRow);
    scatter_kernel<<<782, 256, 0, stream>>>(pool_src, pool_dst, pool_attr, NPOOL,
                                            poolNext, poolPk);
    scatter_kernel<<<3125, 256, 0, stream>>>(edge_src, edge_dst, edge_attr, NEDGE,
                                             edgeNext, edgePk);

    // ---- pipeline: each conv = dense (z in-place over h, g -> G) + gather (in-place) ----
    pool_kernel<<<NB, 256, 0, stream>>>(x, P, poolRow, poolPk);

    dense_kernel<false><<<2048, 256, 0, stream>>>(P, P, G, Wr1, Wn1, b1, nullptr);
    gather_kernel<false><<<NB, 256, 0, stream>>>(P, G, P, edgeRow, edgePk);

    dense_kernel<false><<<2048, 256, 0, stream>>>(P, P, G, Wr2, Wn2, b2, nullptr);
    gather_kernel<false><<<NB, 256, 0, stream>>>(P, G, P, edgeRow, edgePk);

    stats_kernel<<<200, 256, 0, stream>>>(P, stats);
    stats_fin<<<1, 128, 0, stream>>>(stats);

    dense_kernel<true><<<2048, 256, 0, stream>>>(P, P, G, Wr3, Wn3, b3, stats);
    gather_kernel<false><<<NB, 256, 0, stream>>>(P, G, P, edgeRow, edgePk);

    dense_kernel<false><<<2048, 256, 0, stream>>>(P, P, G, Wr4, Wn4, b4, nullptr);
    if (bigws) {
        gather_kernel<true><<<NB, 256, 0, stream>>>(P, G, out, edgeRow, edgePk);
    } else {
        gather_kernel<false><<<NB, 256, 0, stream>>>(P, G, P, edgeRow, edgePk);
        transpose_kernel<<<NB, 256, 0, stream>>>(P, G);   // P==d_out (NCB) -> G (BNC)
        hipMemcpyAsync(out, G, BUFB, hipMemcpyDeviceToDevice, stream);
    }
}